// Round 1
// baseline (699.315 us; speedup 1.0000x reference)
//
#include <hip/hip_runtime.h>
#include <math.h>

#define B_ 8
#define T_ 2048
#define C_ 1024
#define H_ 128

#define R_ 16            // x rows per block in projection kernel
#define TQ 64            // q rows per attention block
#define TK 32            // k/v rows per tile
#define HP (H_ + 4)      // padded LDS row stride (floats), 16B-aligned

// ---------------------------------------------------------------------------
// Kernel 1: q/k/v = x @ W{q,k,v} + b{q,k,v}
// grid: (B*T)/R_ blocks, 256 threads.
// thread: h = tid & 127 owns one output column; half = tid>>7 owns 8 rows.
// x rows staged in LDS; reads are wave-broadcast (conflict-free).
// ---------------------------------------------------------------------------
__global__ __launch_bounds__(256) void qkv_proj(
    const float* __restrict__ x,
    const float* __restrict__ Wq, const float* __restrict__ bq,
    const float* __restrict__ Wk, const float* __restrict__ bk,
    const float* __restrict__ Wv, const float* __restrict__ bv,
    float* __restrict__ q, float* __restrict__ k, float* __restrict__ v)
{
    __shared__ float xs[R_][C_];          // 64 KB
    const int tid = threadIdx.x;
    const long row0 = (long)blockIdx.x * R_;

    // stage 16 rows of x (coalesced float4)
    const float4* xg = (const float4*)(x + row0 * C_);
    float4* xls = (float4*)xs;
    #pragma unroll
    for (int i = tid; i < R_ * C_ / 4; i += 256) xls[i] = xg[i];
    __syncthreads();

    const int h = tid & 127;
    const int half = tid >> 7;            // rows half*8 .. half*8+7
    float aq[8], ak[8], av[8];
    #pragma unroll
    for (int r = 0; r < 8; ++r) { aq[r] = 0.f; ak[r] = 0.f; av[r] = 0.f; }

    for (int c = 0; c < C_; c += 4) {
        float4 xv[8];
        #pragma unroll
        for (int r = 0; r < 8; ++r)
            xv[r] = *(const float4*)&xs[half * 8 + r][c];
        #pragma unroll
        for (int dc = 0; dc < 4; ++dc) {
            const float wq = Wq[(size_t)(c + dc) * H_ + h];
            const float wk = Wk[(size_t)(c + dc) * H_ + h];
            const float wv = Wv[(size_t)(c + dc) * H_ + h];
            #pragma unroll
            for (int r = 0; r < 8; ++r) {
                const float xr = ((const float*)&xv[r])[dc];
                aq[r] = fmaf(xr, wq, aq[r]);
                ak[r] = fmaf(xr, wk, ak[r]);
                av[r] = fmaf(xr, wv, av[r]);
            }
        }
    }
    const float bqv = bq[h], bkv = bk[h], bvv = bv[h];
    #pragma unroll
    for (int r = 0; r < 8; ++r) {
        const size_t orow = (size_t)row0 + half * 8 + r;
        q[orow * H_ + h] = aq[r] + bqv;
        k[orow * H_ + h] = ak[r] + bkv;
        v[orow * H_ + h] = av[r] + bvv;
    }
}

// ---------------------------------------------------------------------------
// Kernel 2: causal flash attention, fp32.
// grid: (T/TQ, B) = (32, 8); 256 threads/block.
// thread (ti = tid>>3 in 0..31, tj = tid&7 in 0..7):
//   S rows  i0 = 2*ti, i0+1 ; S cols j = tj + 8*jj (jj=0..3)  [K-read conflict-free]
//   O rows  i0, i0+1        ; O cols tj*4 + 32*c4 (+0..3)     [V-read conflict-free]
// ---------------------------------------------------------------------------
__global__ __launch_bounds__(256) void attn(
    const float* __restrict__ q, const float* __restrict__ k,
    const float* __restrict__ v, float* __restrict__ out)
{
    __shared__ float Qs[TQ][HP];          // 33 KB
    __shared__ float Ks[TK][HP];          // 16.5 KB
    __shared__ float Vs[TK][HP];          // 16.5 KB
    __shared__ float Ss[TQ][TK + 1];      // 8.25 KB
    __shared__ float m_s[TQ], l_s[TQ], sc_s[TQ];

    const int tid = threadIdx.x;
    const int b  = blockIdx.y;
    const int t0 = blockIdx.x * TQ;

    const float* qb = q + (size_t)b * T_ * H_;
    const float* kb = k + (size_t)b * T_ * H_;
    const float* vb = v + (size_t)b * T_ * H_;

    // stage Q tile
    for (int i = tid; i < TQ * H_ / 4; i += 256) {
        const int r  = i >> 5;            // H_/4 = 32 float4 per row
        const int c4 = i & 31;
        *(float4*)&Qs[r][c4 * 4] =
            *(const float4*)&qb[(size_t)(t0 + r) * H_ + c4 * 4];
    }
    if (tid < TQ) { m_s[tid] = -INFINITY; l_s[tid] = 0.f; }

    const int ti = tid >> 3;
    const int tj = tid & 7;
    const int i0 = ti * 2;

    float O[2][16];
    #pragma unroll
    for (int a = 0; a < 2; ++a)
        #pragma unroll
        for (int cc = 0; cc < 16; ++cc) O[a][cc] = 0.f;

    const int nkt = t0 / TK + 2;          // causal: k range [0, t0+TQ)
    for (int kt = 0; kt < nkt; ++kt) {
        const int s0 = kt * TK;
        __syncthreads();                  // prev iter done with Ks/Vs (and Q staged)
        for (int i = tid; i < TK * H_ / 4; i += 256) {
            const int r  = i >> 5;
            const int c4 = i & 31;
            *(float4*)&Ks[r][c4 * 4] =
                *(const float4*)&kb[(size_t)(s0 + r) * H_ + c4 * 4];
            *(float4*)&Vs[r][c4 * 4] =
                *(const float4*)&vb[(size_t)(s0 + r) * H_ + c4 * 4];
        }
        __syncthreads();

        // ---- S = Q K^T (2 rows x 4 interleaved cols per thread) ----
        float acc[2][4] = {{0.f,0.f,0.f,0.f},{0.f,0.f,0.f,0.f}};
        #pragma unroll 4
        for (int c = 0; c < H_; c += 4) {
            const float4 q0 = *(const float4*)&Qs[i0][c];
            const float4 q1 = *(const float4*)&Qs[i0 + 1][c];
            #pragma unroll
            for (int jj = 0; jj < 4; ++jj) {
                const float4 kv = *(const float4*)&Ks[tj + 8 * jj][c];
                acc[0][jj] = fmaf(q0.x, kv.x, acc[0][jj]);
                acc[0][jj] = fmaf(q0.y, kv.y, acc[0][jj]);
                acc[0][jj] = fmaf(q0.z, kv.z, acc[0][jj]);
                acc[0][jj] = fmaf(q0.w, kv.w, acc[0][jj]);
                acc[1][jj] = fmaf(q1.x, kv.x, acc[1][jj]);
                acc[1][jj] = fmaf(q1.y, kv.y, acc[1][jj]);
                acc[1][jj] = fmaf(q1.z, kv.z, acc[1][jj]);
                acc[1][jj] = fmaf(q1.w, kv.w, acc[1][jj]);
            }
        }
        // causal mask + store scores
        #pragma unroll
        for (int a = 0; a < 2; ++a) {
            const int tg = t0 + i0 + a;
            #pragma unroll
            for (int jj = 0; jj < 4; ++jj) {
                const int j  = tj + 8 * jj;
                const int sg = s0 + j;
                Ss[i0 + a][j] = (sg <= tg) ? acc[a][jj] : -INFINITY;
            }
        }
        __syncthreads();

        // ---- online softmax (one thread per row) ----
        if (tid < TQ) {
            const float mo = m_s[tid];
            float mx = mo;
            #pragma unroll
            for (int j = 0; j < TK; ++j) mx = fmaxf(mx, Ss[tid][j]);
            const float sc = __expf(mo - mx);      // 0 when mo = -inf
            float l = l_s[tid] * sc;
            #pragma unroll
            for (int j = 0; j < TK; ++j) {
                const float p = __expf(Ss[tid][j] - mx);   // masked -> 0
                Ss[tid][j] = p;
                l += p;
            }
            m_s[tid] = mx; l_s[tid] = l; sc_s[tid] = sc;
        }
        __syncthreads();

        // ---- rescale O, accumulate P @ V ----
        const float sA = sc_s[i0], sB = sc_s[i0 + 1];
        #pragma unroll
        for (int cc = 0; cc < 16; ++cc) { O[0][cc] *= sA; O[1][cc] *= sB; }
        #pragma unroll 4
        for (int s = 0; s < TK; ++s) {
            const float p0 = Ss[i0][s];
            const float p1 = Ss[i0 + 1][s];
            #pragma unroll
            for (int c4 = 0; c4 < 4; ++c4) {
                const float4 vv = *(const float4*)&Vs[s][tj * 4 + 32 * c4];
                O[0][c4*4+0] = fmaf(p0, vv.x, O[0][c4*4+0]);
                O[0][c4*4+1] = fmaf(p0, vv.y, O[0][c4*4+1]);
                O[0][c4*4+2] = fmaf(p0, vv.z, O[0][c4*4+2]);
                O[0][c4*4+3] = fmaf(p0, vv.w, O[0][c4*4+3]);
                O[1][c4*4+0] = fmaf(p1, vv.x, O[1][c4*4+0]);
                O[1][c4*4+1] = fmaf(p1, vv.y, O[1][c4*4+1]);
                O[1][c4*4+2] = fmaf(p1, vv.z, O[1][c4*4+2]);
                O[1][c4*4+3] = fmaf(p1, vv.w, O[1][c4*4+3]);
            }
        }
    }

    // ---- epilogue: out = O / l ----
    const float inv0 = 1.f / l_s[i0];
    const float inv1 = 1.f / l_s[i0 + 1];
    float* ob = out + ((size_t)b * T_ + t0) * H_;
    #pragma unroll
    for (int c4 = 0; c4 < 4; ++c4) {
        float4 o0, o1;
        o0.x = O[0][c4*4+0] * inv0; o0.y = O[0][c4*4+1] * inv0;
        o0.z = O[0][c4*4+2] * inv0; o0.w = O[0][c4*4+3] * inv0;
        o1.x = O[1][c4*4+0] * inv1; o1.y = O[1][c4*4+1] * inv1;
        o1.z = O[1][c4*4+2] * inv1; o1.w = O[1][c4*4+3] * inv1;
        *(float4*)&ob[(size_t)(i0)     * H_ + tj * 4 + 32 * c4] = o0;
        *(float4*)&ob[(size_t)(i0 + 1) * H_ + tj * 4 + 32 * c4] = o1;
    }
}

// ---------------------------------------------------------------------------
extern "C" void kernel_launch(void* const* d_in, const int* in_sizes, int n_in,
                              void* d_out, int out_size, void* d_ws, size_t ws_size,
                              hipStream_t stream)
{
    const float* x  = (const float*)d_in[0];
    const float* Wq = (const float*)d_in[1];
    const float* bq = (const float*)d_in[2];
    const float* Wk = (const float*)d_in[3];
    const float* bk = (const float*)d_in[4];
    const float* Wv = (const float*)d_in[5];
    const float* bv = (const float*)d_in[6];
    float* out = (float*)d_out;

    // workspace: q,k,v  each B*T*H floats (8 MB) -> 24 MB total
    float* q = (float*)d_ws;
    float* k = q + (size_t)B_ * T_ * H_;
    float* v = k + (size_t)B_ * T_ * H_;

    qkv_proj<<<dim3((B_ * T_) / R_), dim3(256), 0, stream>>>(
        x, Wq, bq, Wk, bk, Wv, bv, q, k, v);
    attn<<<dim3(T_ / TQ, B_), dim3(256), 0, stream>>>(q, k, v, out);
}

// Round 2
// 427.010 us; speedup vs baseline: 1.6377x; 1.6377x over previous
//
#include <hip/hip_runtime.h>
#include <math.h>

#define B_ 8
#define T_ 2048
#define C_ 1024
#define H_ 128

#define R_ 16            // x rows per block in projection kernel
#define TQA 32           // q rows per attention block (2 waves x 16)
#define TKA 64           // k/v rows per tile

typedef __attribute__((ext_vector_type(8))) short short8;
typedef __attribute__((ext_vector_type(4))) float f32x4;

__device__ __forceinline__ short f2bf(float f) {
    unsigned u = __float_as_uint(f);
    u += 0x7fffu + ((u >> 16) & 1u);       // RNE
    return (short)(u >> 16);
}
__device__ __forceinline__ float bf2f(short s) {
    return __uint_as_float(((unsigned)(unsigned short)s) << 16);
}

// ---------------------------------------------------------------------------
// Kernel 1: q/k/v = x @ W{q,k,v} + b{q,k,v}; outputs hi/lo-split bf16 for q,k
// and bf16 for v.  grid: (B*T)/R_ blocks, 256 threads.
// ---------------------------------------------------------------------------
__global__ __launch_bounds__(256) void qkv_proj(
    const float* __restrict__ x,
    const float* __restrict__ Wq, const float* __restrict__ bq,
    const float* __restrict__ Wk, const float* __restrict__ bk,
    const float* __restrict__ Wv, const float* __restrict__ bv,
    short* __restrict__ qh, short* __restrict__ ql,
    short* __restrict__ kh, short* __restrict__ kl,
    short* __restrict__ vh)
{
    __shared__ float xs[R_][C_];          // 64 KB
    const int tid = threadIdx.x;
    const long row0 = (long)blockIdx.x * R_;

    const float4* xg = (const float4*)(x + row0 * C_);
    float4* xls = (float4*)xs;
    for (int i = tid; i < R_ * C_ / 4; i += 256) xls[i] = xg[i];
    __syncthreads();

    const int h = tid & 127;
    const int half = tid >> 7;            // rows half*8 .. half*8+7
    float aq[8], ak[8], av[8];
    #pragma unroll
    for (int r = 0; r < 8; ++r) { aq[r] = 0.f; ak[r] = 0.f; av[r] = 0.f; }

    for (int c = 0; c < C_; c += 4) {
        float4 xv[8];
        #pragma unroll
        for (int r = 0; r < 8; ++r)
            xv[r] = *(const float4*)&xs[half * 8 + r][c];
        #pragma unroll
        for (int dc = 0; dc < 4; ++dc) {
            const float wq = Wq[(size_t)(c + dc) * H_ + h];
            const float wk = Wk[(size_t)(c + dc) * H_ + h];
            const float wv = Wv[(size_t)(c + dc) * H_ + h];
            #pragma unroll
            for (int r = 0; r < 8; ++r) {
                const float xr = ((const float*)&xv[r])[dc];
                aq[r] = fmaf(xr, wq, aq[r]);
                ak[r] = fmaf(xr, wk, ak[r]);
                av[r] = fmaf(xr, wv, av[r]);
            }
        }
    }
    const float bqv = bq[h], bkv = bk[h], bvv = bv[h];
    #pragma unroll
    for (int r = 0; r < 8; ++r) {
        const size_t o = ((size_t)row0 + half * 8 + r) * H_ + h;
        const float qv = aq[r] + bqv;
        const float kv = ak[r] + bkv;
        const float vv = av[r] + bvv;
        const short qhi = f2bf(qv);
        const short khi = f2bf(kv);
        qh[o] = qhi; ql[o] = f2bf(qv - bf2f(qhi));
        kh[o] = khi; kl[o] = f2bf(kv - bf2f(khi));
        vh[o] = f2bf(vv);
    }
}

// ---------------------------------------------------------------------------
// Kernel 2: causal flash attention with bf16 MFMA.
// grid (64, 8), 128 threads = 2 waves; wave w owns q rows t0+w*16 .. +15.
// tile = 63 - blockIdx.x  (LPT: longest blocks dispatch first).
// QK^T: 3-term hi/lo split (fp32-accurate scores). PV: bf16 P, bf16 V.
// K LDS [64][128] bf16 hi/lo, XOR-swizzled (^((key&7)<<3) on short index).
// V LDS transposed [128 h][64 key], XOR-swizzled (^((h&7)<<3)).
// ---------------------------------------------------------------------------
__global__ __launch_bounds__(128) void attn_mfma(
    const short* __restrict__ qhg, const short* __restrict__ qlg,
    const short* __restrict__ khg, const short* __restrict__ klg,
    const short* __restrict__ vhg, float* __restrict__ out)
{
    __shared__ short Kh[TKA * 128];       // 16 KB
    __shared__ short Kl[TKA * 128];       // 16 KB
    __shared__ short Vt[128 * TKA];       // 16 KB
    __shared__ short Pb[2][16 * 72];      // 4.5 KB, row stride 72 (144B, 16B-mult)

    const int tid  = threadIdx.x;
    const int lane = tid & 63;
    const int w    = tid >> 6;
    const int lg   = lane >> 4;           // 0..3
    const int lc   = lane & 15;           // 0..15
    const int b    = blockIdx.y;
    const int tile = 63 - (int)blockIdx.x;
    const int t0   = tile * TQA;

    const size_t bo = (size_t)b * T_ * H_;

    // ---- Q fragments (A-layout: row = lc, k = lg*8+j within 32-chunk) ----
    short8 qfh[4], qfl[4];
    {
        const size_t rbase = bo + (size_t)(t0 + w * 16 + lc) * H_;
        #pragma unroll
        for (int kc = 0; kc < 4; ++kc) {
            qfh[kc] = *(const short8*)(qhg + rbase + kc * 32 + lg * 8);
            qfl[kc] = *(const short8*)(qlg + rbase + kc * 32 + lg * 8);
        }
    }

    f32x4 Oacc[8];
    #pragma unroll
    for (int ht = 0; ht < 8; ++ht) Oacc[ht] = (f32x4){0.f, 0.f, 0.f, 0.f};
    float m_run[4] = {-INFINITY, -INFINITY, -INFINITY, -INFINITY};
    float l_run[4] = {0.f, 0.f, 0.f, 0.f};

    const int nkt = (tile >> 1) + 1;      // key tiles of 64 covering [0, t0+32)
    for (int kt = 0; kt < nkt; ++kt) {
        const int s0 = kt * TKA;
        __syncthreads();                  // prev tile fully consumed

        // ---- stage K hi/lo (coalesced reads, swizzled b128 LDS writes) ----
        #pragma unroll
        for (int it = 0; it < 8; ++it) {
            const int i  = tid + it * 128;       // 0..1023
            const int key = i >> 4;
            const int h0  = (i & 15) * 8;
            const size_t g = bo + (size_t)(s0 + key) * H_ + h0;
            const short8 a = *(const short8*)(khg + g);
            const short8 c = *(const short8*)(klg + g);
            const int idx = (key * 128 + h0) ^ ((key & 7) << 3);
            *(short8*)&Kh[idx] = a;
            *(short8*)&Kl[idx] = c;
        }
        // ---- stage V transposed (L1-hot reads, 2-way-free scalar writes) ----
        #pragma unroll
        for (int it = 0; it < 8; ++it) {
            const int i  = tid + it * 128;
            const int r  = i & 63;
            const int h0 = (i >> 6) * 8;
            const short8 a = *(const short8*)(vhg + bo + (size_t)(s0 + r) * H_ + h0);
            #pragma unroll
            for (int j = 0; j < 8; ++j) {
                const int h = h0 + j;
                Vt[(h * 64 + r) ^ ((h & 7) << 3)] = a[j];
            }
        }
        __syncthreads();

        // ---- S = Q K^T : 4 col-tiles x 4 k-chunks x 3 hi/lo terms ----
        f32x4 sfr[4];
        #pragma unroll
        for (int ct = 0; ct < 4; ++ct) sfr[ct] = (f32x4){0.f, 0.f, 0.f, 0.f};
        #pragma unroll
        for (int kc = 0; kc < 4; ++kc) {
            const int hoff = kc * 32 + lg * 8;
            #pragma unroll
            for (int ct = 0; ct < 4; ++ct) {
                const int key = ct * 16 + lc;
                const int idx = (key * 128 + hoff) ^ ((key & 7) << 3);
                const short8 bh = *(const short8*)&Kh[idx];
                const short8 bl = *(const short8*)&Kl[idx];
                sfr[ct] = __builtin_amdgcn_mfma_f32_16x16x32_bf16(qfh[kc], bh, sfr[ct], 0, 0, 0);
                sfr[ct] = __builtin_amdgcn_mfma_f32_16x16x32_bf16(qfl[kc], bh, sfr[ct], 0, 0, 0);
                sfr[ct] = __builtin_amdgcn_mfma_f32_16x16x32_bf16(qfh[kc], bl, sfr[ct], 0, 0, 0);
            }
        }

        // ---- causal mask (last tile only) ----
        if (kt == nkt - 1) {
            #pragma unroll
            for (int ct = 0; ct < 4; ++ct) {
                const int key_g = s0 + ct * 16 + lc;
                #pragma unroll
                for (int r = 0; r < 4; ++r) {
                    const int row_g = t0 + w * 16 + lg * 4 + r;
                    if (key_g > row_g) sfr[ct][r] = -INFINITY;
                }
            }
        }

        // ---- online softmax (rows live in 16-lane groups; shfl_xor reduce) ----
        float mx[4];
        #pragma unroll
        for (int r = 0; r < 4; ++r)
            mx[r] = fmaxf(fmaxf(sfr[0][r], sfr[1][r]), fmaxf(sfr[2][r], sfr[3][r]));
        #pragma unroll
        for (int d = 1; d < 16; d <<= 1)
            #pragma unroll
            for (int r = 0; r < 4; ++r)
                mx[r] = fmaxf(mx[r], __shfl_xor(mx[r], d, 64));

        float sc[4];
        #pragma unroll
        for (int r = 0; r < 4; ++r) {
            const float mnew = fmaxf(m_run[r], mx[r]);
            sc[r] = __expf(m_run[r] - mnew);   // 0 on first tile
            m_run[r] = mnew;
        }
        float sum[4] = {0.f, 0.f, 0.f, 0.f};
        #pragma unroll
        for (int ct = 0; ct < 4; ++ct)
            #pragma unroll
            for (int r = 0; r < 4; ++r) {
                const float p = __expf(sfr[ct][r] - m_run[r]);  // masked -> 0
                sfr[ct][r] = p;
                sum[r] += p;
            }
        #pragma unroll
        for (int d = 1; d < 16; d <<= 1)
            #pragma unroll
            for (int r = 0; r < 4; ++r)
                sum[r] += __shfl_xor(sum[r], d, 64);
        #pragma unroll
        for (int r = 0; r < 4; ++r)
            l_run[r] = l_run[r] * sc[r] + sum[r];

        // ---- rescale O, write P (bf16) to this wave's LDS buffer ----
        #pragma unroll
        for (int ht = 0; ht < 8; ++ht)
            #pragma unroll
            for (int r = 0; r < 4; ++r) Oacc[ht][r] *= sc[r];

        short* P = &Pb[w][0];
        #pragma unroll
        for (int ct = 0; ct < 4; ++ct)
            #pragma unroll
            for (int r = 0; r < 4; ++r)
                P[(lg * 4 + r) * 72 + ct * 16 + lc] = f2bf(sfr[ct][r]);

        // ---- O += P @ V  (A = P row=lc; B = V^T from Vt) ----
        #pragma unroll
        for (int kc2 = 0; kc2 < 2; ++kc2) {
            const short8 pa = *(const short8*)&P[lc * 72 + kc2 * 32 + lg * 8];
            #pragma unroll
            for (int ht = 0; ht < 8; ++ht) {
                const int h = ht * 16 + lc;
                const int idx = (h * 64 + kc2 * 32 + lg * 8) ^ ((h & 7) << 3);
                const short8 vb = *(const short8*)&Vt[idx];
                Oacc[ht] = __builtin_amdgcn_mfma_f32_16x16x32_bf16(pa, vb, Oacc[ht], 0, 0, 0);
            }
        }
    }

    // ---- epilogue: out = O / l ----
    float inv[4];
    #pragma unroll
    for (int r = 0; r < 4; ++r) inv[r] = 1.f / l_run[r];
    float* ob = out + bo + (size_t)(t0 + w * 16) * H_;
    #pragma unroll
    for (int ht = 0; ht < 8; ++ht)
        #pragma unroll
        for (int r = 0; r < 4; ++r)
            ob[(size_t)(lg * 4 + r) * H_ + ht * 16 + lc] = Oacc[ht][r] * inv[r];
}

// ---------------------------------------------------------------------------
extern "C" void kernel_launch(void* const* d_in, const int* in_sizes, int n_in,
                              void* d_out, int out_size, void* d_ws, size_t ws_size,
                              hipStream_t stream)
{
    const float* x  = (const float*)d_in[0];
    const float* Wq = (const float*)d_in[1];
    const float* bq = (const float*)d_in[2];
    const float* Wk = (const float*)d_in[3];
    const float* bk = (const float*)d_in[4];
    const float* Wv = (const float*)d_in[5];
    const float* bv = (const float*)d_in[6];
    float* out = (float*)d_out;

    // workspace: 5 bf16 arrays of B*T*H (4 MB each) = 20 MB
    const size_t SZ = (size_t)B_ * T_ * H_;
    short* qh = (short*)d_ws;
    short* ql = qh + SZ;
    short* kh = ql + SZ;
    short* kl = kh + SZ;
    short* vh = kl + SZ;

    qkv_proj<<<dim3((B_ * T_) / R_), dim3(256), 0, stream>>>(
        x, Wq, bq, Wk, bk, Wv, bv, qh, ql, kh, kl, vh);
    attn_mfma<<<dim3(T_ / TQA, B_), dim3(128), 0, stream>>>(
        qh, ql, kh, kl, vh, out);
}

// Round 4
// 251.006 us; speedup vs baseline: 2.7861x; 1.7012x over previous
//
#include <hip/hip_runtime.h>
#include <math.h>

#define B_ 8
#define T_ 2048
#define C_ 1024
#define H_ 128

#define TQA 32           // q rows per attention block (2 waves x 16)
#define TKA 64           // k/v rows per tile

#define BM 128
#define BN 128
#define BK 64

typedef __attribute__((ext_vector_type(8))) short s16x8;
typedef __attribute__((ext_vector_type(4))) short s16x4;
typedef __attribute__((ext_vector_type(4))) float f32x4;

__device__ __forceinline__ short f2bf(float f) {
    unsigned u = __float_as_uint(f);
    u += 0x7fffu + ((u >> 16) & 1u);       // RNE
    return (short)(u >> 16);
}
__device__ __forceinline__ float bf2f(short s) {
    return __uint_as_float(((unsigned)(unsigned short)s) << 16);
}

// ---------------------------------------------------------------------------
// Kernel 0: W prep — transpose W[k][h] (q,k,v) into Wt[n][k] hi/lo bf16,
// n = mat*128 + h.  Reads 1.5 MB, writes 1.5 MB. Trivial cost.
// ---------------------------------------------------------------------------
__global__ __launch_bounds__(256) void wprep(
    const float* __restrict__ Wq, const float* __restrict__ Wk,
    const float* __restrict__ Wv,
    short* __restrict__ Wth, short* __restrict__ Wtl)
{
    const int n   = blockIdx.x;           // 0..383
    const int mat = n >> 7;
    const int h   = n & 127;
    const float* W = (mat == 0) ? Wq : (mat == 1) ? Wk : Wv;
    for (int k = threadIdx.x; k < C_; k += 256) {
        const float w = W[(size_t)k * H_ + h];
        const short hi = f2bf(w);
        Wth[(size_t)n * C_ + k] = hi;
        Wtl[(size_t)n * C_ + k] = f2bf(w - bf2f(hi));
    }
}

// ---------------------------------------------------------------------------
// Kernel 1: 3-term hi/lo bf16 MFMA GEMM:  [16384 x 1024] @ [1024 x 128] x3.
// grid (128, 3): blockIdx.x = M-block, blockIdx.y = matrix (q/k/v).
// 256 threads = 4 waves (2x2), wave tile 64x64, acc[4][4] f32x4.
// LDS [row][64] bf16, XOR-swizzle slot ^= (row&7) -> conflict-free b128.
// x prefetched to regs (T14-lite); W loads are L1/L2-hot.
// Epilogue: +bias (fp32), split to qh/ql/kh/kl/vh bf16.
// ---------------------------------------------------------------------------
__global__ __launch_bounds__(256, 2) void gemm_proj(
    const float* __restrict__ x,
    const short* __restrict__ Wth, const short* __restrict__ Wtl,
    const float* __restrict__ bq, const float* __restrict__ bk,
    const float* __restrict__ bv,
    short* __restrict__ qh, short* __restrict__ ql,
    short* __restrict__ kh, short* __restrict__ kl,
    short* __restrict__ vh)
{
    __shared__ short Ah[BM * BK];         // 16 KB each
    __shared__ short Al[BM * BK];
    __shared__ short Bh[BN * BK];
    __shared__ short Bl[BN * BK];

    const int tid  = threadIdx.x;
    const int my   = blockIdx.y;
    const long m0  = (long)blockIdx.x * BM;
    const int lane = tid & 63;
    const int w    = tid >> 6;
    const int wr   = w >> 1, wc = w & 1;
    const int lg   = lane >> 4, lc = lane & 15;

    float4 xr[8];                         // prefetched x tile (this thread's part)

    // ---- load x tile (rows m0.., cols k0..k0+63) into regs, coalesced ----
    #define LOAD_X(k0)                                                        \
        _Pragma("unroll")                                                     \
        for (int it = 0; it < 8; ++it) {                                      \
            const int i  = tid + it * 256;                                    \
            const int r  = i >> 4;                                            \
            const int k4 = i & 15;                                            \
            xr[it] = *(const float4*)&x[(m0 + r) * C_ + (k0) + k4 * 4];       \
        }

    // ---- convert prefetched x to hi/lo + stage; stage W (L1-hot) ----
    #define STORE_LDS(k0)                                                     \
        _Pragma("unroll")                                                     \
        for (int it = 0; it < 8; ++it) {                                      \
            const int i  = tid + it * 256;                                    \
            const int r  = i >> 4;                                            \
            const int k4 = i & 15;                                            \
            s16x4 hi4, lo4;                                                   \
            _Pragma("unroll")                                                 \
            for (int j = 0; j < 4; ++j) {                                     \
                const float f = ((const float*)&xr[it])[j];                   \
                const short h8 = f2bf(f);                                     \
                hi4[j] = h8; lo4[j] = f2bf(f - bf2f(h8));                     \
            }                                                                 \
            const int off = r * 64 + (((k4 >> 1) ^ (r & 7)) << 3)             \
                          + ((k4 & 1) << 2);                                  \
            *(s16x4*)&Ah[off] = hi4;                                          \
            *(s16x4*)&Al[off] = lo4;                                          \
        }                                                                     \
        _Pragma("unroll")                                                     \
        for (int it = 0; it < 4; ++it) {                                      \
            const int i = tid + it * 256;                                     \
            const int r = i >> 3;                                             \
            const int s = i & 7;                                              \
            const size_t g = (size_t)(my * BN + r) * C_ + (k0) + s * 8;       \
            const int off = r * 64 + ((s ^ (r & 7)) << 3);                    \
            *(s16x8*)&Bh[off] = *(const s16x8*)&Wth[g];                       \
            *(s16x8*)&Bl[off] = *(const s16x8*)&Wtl[g];                       \
        }

    f32x4 acc[4][4];
    #pragma unroll
    for (int m = 0; m < 4; ++m)
        #pragma unroll
        for (int n = 0; n < 4; ++n) acc[m][n] = (f32x4){0.f, 0.f, 0.f, 0.f};

    LOAD_X(0);
    STORE_LDS(0);
    __syncthreads();

    for (int kt = 0; kt < C_ / BK; ++kt) {
        if (kt < C_ / BK - 1) LOAD_X((kt + 1) * BK);

        #pragma unroll
        for (int kc = 0; kc < 2; ++kc) {
            s16x8 afh[4], afl[4], bfh[4], bfl[4];
            #pragma unroll
            for (int m = 0; m < 4; ++m) {
                const int r = wr * 64 + m * 16 + lc;
                const int off = r * 64 + ((((kc << 2) + lg) ^ (r & 7)) << 3);
                afh[m] = *(const s16x8*)&Ah[off];
                afl[m] = *(const s16x8*)&Al[off];
            }
            #pragma unroll
            for (int n = 0; n < 4; ++n) {
                const int r = wc * 64 + n * 16 + lc;
                const int off = r * 64 + ((((kc << 2) + lg) ^ (r & 7)) << 3);
                bfh[n] = *(const s16x8*)&Bh[off];
                bfl[n] = *(const s16x8*)&Bl[off];
            }
            #pragma unroll
            for (int m = 0; m < 4; ++m)
                #pragma unroll
                for (int n = 0; n < 4; ++n) {
                    acc[m][n] = __builtin_amdgcn_mfma_f32_16x16x32_bf16(afh[m], bfh[n], acc[m][n], 0, 0, 0);
                    acc[m][n] = __builtin_amdgcn_mfma_f32_16x16x32_bf16(afh[m], bfl[n], acc[m][n], 0, 0, 0);
                    acc[m][n] = __builtin_amdgcn_mfma_f32_16x16x32_bf16(afl[m], bfh[n], acc[m][n], 0, 0, 0);
                }
        }
        __syncthreads();
        if (kt < C_ / BK - 1) {
            STORE_LDS((kt + 1) * BK);
            __syncthreads();
        }
    }

    // ---- epilogue: +bias, hi/lo split, store ----
    const float* bias = (my == 0) ? bq : (my == 1) ? bk : bv;
    short* oh = (my == 0) ? qh : (my == 1) ? kh : vh;
    short* ol = (my == 0) ? ql : kl;      // unused when my==2

    #pragma unroll
    for (int n = 0; n < 4; ++n) {
        const int h = wc * 64 + n * 16 + lc;
        const float bv_ = bias[h];
        #pragma unroll
        for (int m = 0; m < 4; ++m) {
            #pragma unroll
            for (int rr = 0; rr < 4; ++rr) {
                const long row = m0 + wr * 64 + m * 16 + lg * 4 + rr;
                const float val = acc[m][n][rr] + bv_;
                const short hi = f2bf(val);
                oh[(size_t)row * H_ + h] = hi;
                if (my < 2) ol[(size_t)row * H_ + h] = f2bf(val - bf2f(hi));
            }
        }
    }
}

// ---------------------------------------------------------------------------
// Kernel 2: causal flash attention with bf16 MFMA (unchanged from round 2).
// ---------------------------------------------------------------------------
__global__ __launch_bounds__(128) void attn_mfma(
    const short* __restrict__ qhg, const short* __restrict__ qlg,
    const short* __restrict__ khg, const short* __restrict__ klg,
    const short* __restrict__ vhg, float* __restrict__ out)
{
    __shared__ short Kh[TKA * 128];       // 16 KB
    __shared__ short Kl[TKA * 128];       // 16 KB
    __shared__ short Vt[128 * TKA];       // 16 KB
    __shared__ short Pb[2][16 * 72];      // 4.5 KB

    const int tid  = threadIdx.x;
    const int lane = tid & 63;
    const int w    = tid >> 6;
    const int lg   = lane >> 4;
    const int lc   = lane & 15;
    const int b    = blockIdx.y;
    const int tile = 63 - (int)blockIdx.x;
    const int t0   = tile * TQA;

    const size_t bo = (size_t)b * T_ * H_;

    s16x8 qfh[4], qfl[4];
    {
        const size_t rbase = bo + (size_t)(t0 + w * 16 + lc) * H_;
        #pragma unroll
        for (int kc = 0; kc < 4; ++kc) {
            qfh[kc] = *(const s16x8*)(qhg + rbase + kc * 32 + lg * 8);
            qfl[kc] = *(const s16x8*)(qlg + rbase + kc * 32 + lg * 8);
        }
    }

    f32x4 Oacc[8];
    #pragma unroll
    for (int ht = 0; ht < 8; ++ht) Oacc[ht] = (f32x4){0.f, 0.f, 0.f, 0.f};
    float m_run[4] = {-INFINITY, -INFINITY, -INFINITY, -INFINITY};
    float l_run[4] = {0.f, 0.f, 0.f, 0.f};

    const int nkt = (tile >> 1) + 1;
    for (int kt = 0; kt < nkt; ++kt) {
        const int s0 = kt * TKA;
        __syncthreads();

        #pragma unroll
        for (int it = 0; it < 8; ++it) {
            const int i  = tid + it * 128;
            const int key = i >> 4;
            const int h0  = (i & 15) * 8;
            const size_t g = bo + (size_t)(s0 + key) * H_ + h0;
            const s16x8 a = *(const s16x8*)(khg + g);
            const s16x8 c = *(const s16x8*)(klg + g);
            const int idx = (key * 128 + h0) ^ ((key & 7) << 3);
            *(s16x8*)&Kh[idx] = a;
            *(s16x8*)&Kl[idx] = c;
        }
        #pragma unroll
        for (int it = 0; it < 8; ++it) {
            const int i  = tid + it * 128;
            const int r  = i & 63;
            const int h0 = (i >> 6) * 8;
            const s16x8 a = *(const s16x8*)(vhg + bo + (size_t)(s0 + r) * H_ + h0);
            #pragma unroll
            for (int j = 0; j < 8; ++j) {
                const int h = h0 + j;
                Vt[(h * 64 + r) ^ ((h & 7) << 3)] = a[j];
            }
        }
        __syncthreads();

        f32x4 sfr[4];
        #pragma unroll
        for (int ct = 0; ct < 4; ++ct) sfr[ct] = (f32x4){0.f, 0.f, 0.f, 0.f};
        #pragma unroll
        for (int kc = 0; kc < 4; ++kc) {
            const int hoff = kc * 32 + lg * 8;
            #pragma unroll
            for (int ct = 0; ct < 4; ++ct) {
                const int key = ct * 16 + lc;
                const int idx = (key * 128 + hoff) ^ ((key & 7) << 3);
                const s16x8 bh = *(const s16x8*)&Kh[idx];
                const s16x8 bl = *(const s16x8*)&Kl[idx];
                sfr[ct] = __builtin_amdgcn_mfma_f32_16x16x32_bf16(qfh[kc], bh, sfr[ct], 0, 0, 0);
                sfr[ct] = __builtin_amdgcn_mfma_f32_16x16x32_bf16(qfl[kc], bh, sfr[ct], 0, 0, 0);
                sfr[ct] = __builtin_amdgcn_mfma_f32_16x16x32_bf16(qfh[kc], bl, sfr[ct], 0, 0, 0);
            }
        }

        if (kt == nkt - 1) {
            #pragma unroll
            for (int ct = 0; ct < 4; ++ct) {
                const int key_g = s0 + ct * 16 + lc;
                #pragma unroll
                for (int r = 0; r < 4; ++r) {
                    const int row_g = t0 + w * 16 + lg * 4 + r;
                    if (key_g > row_g) sfr[ct][r] = -INFINITY;
                }
            }
        }

        float mx[4];
        #pragma unroll
        for (int r = 0; r < 4; ++r)
            mx[r] = fmaxf(fmaxf(sfr[0][r], sfr[1][r]), fmaxf(sfr[2][r], sfr[3][r]));
        #pragma unroll
        for (int d = 1; d < 16; d <<= 1)
            #pragma unroll
            for (int r = 0; r < 4; ++r)
                mx[r] = fmaxf(mx[r], __shfl_xor(mx[r], d, 64));

        float sc[4];
        #pragma unroll
        for (int r = 0; r < 4; ++r) {
            const float mnew = fmaxf(m_run[r], mx[r]);
            sc[r] = __expf(m_run[r] - mnew);
            m_run[r] = mnew;
        }
        float sum[4] = {0.f, 0.f, 0.f, 0.f};
        #pragma unroll
        for (int ct = 0; ct < 4; ++ct)
            #pragma unroll
            for (int r = 0; r < 4; ++r) {
                const float p = __expf(sfr[ct][r] - m_run[r]);
                sfr[ct][r] = p;
                sum[r] += p;
            }
        #pragma unroll
        for (int d = 1; d < 16; d <<= 1)
            #pragma unroll
            for (int r = 0; r < 4; ++r)
                sum[r] += __shfl_xor(sum[r], d, 64);
        #pragma unroll
        for (int r = 0; r < 4; ++r)
            l_run[r] = l_run[r] * sc[r] + sum[r];

        #pragma unroll
        for (int ht = 0; ht < 8; ++ht)
            #pragma unroll
            for (int r = 0; r < 4; ++r) Oacc[ht][r] *= sc[r];

        short* P = &Pb[w][0];
        #pragma unroll
        for (int ct = 0; ct < 4; ++ct)
            #pragma unroll
            for (int r = 0; r < 4; ++r)
                P[(lg * 4 + r) * 72 + ct * 16 + lc] = f2bf(sfr[ct][r]);

        #pragma unroll
        for (int kc2 = 0; kc2 < 2; ++kc2) {
            const s16x8 pa = *(const s16x8*)&P[lc * 72 + kc2 * 32 + lg * 8];
            #pragma unroll
            for (int ht = 0; ht < 8; ++ht) {
                const int h = ht * 16 + lc;
                const int idx = (h * 64 + kc2 * 32 + lg * 8) ^ ((h & 7) << 3);
                const s16x8 vb = *(const s16x8*)&Vt[idx];
                Oacc[ht] = __builtin_amdgcn_mfma_f32_16x16x32_bf16(pa, vb, Oacc[ht], 0, 0, 0);
            }
        }
    }

    float inv[4];
    #pragma unroll
    for (int r = 0; r < 4; ++r) inv[r] = 1.f / l_run[r];
    float* ob = out + bo + (size_t)(t0 + w * 16) * H_;
    #pragma unroll
    for (int ht = 0; ht < 8; ++ht)
        #pragma unroll
        for (int r = 0; r < 4; ++r)
            ob[(size_t)(lg * 4 + r) * H_ + ht * 16 + lc] = Oacc[ht][r] * inv[r];
}

// ---------------------------------------------------------------------------
extern "C" void kernel_launch(void* const* d_in, const int* in_sizes, int n_in,
                              void* d_out, int out_size, void* d_ws, size_t ws_size,
                              hipStream_t stream)
{
    const float* x  = (const float*)d_in[0];
    const float* Wq = (const float*)d_in[1];
    const float* bq = (const float*)d_in[2];
    const float* Wk = (const float*)d_in[3];
    const float* bk = (const float*)d_in[4];
    const float* Wv = (const float*)d_in[5];
    const float* bv = (const float*)d_in[6];
    float* out = (float*)d_out;

    const size_t SZ = (size_t)B_ * T_ * H_;     // 2M elems
    short* qh  = (short*)d_ws;
    short* ql  = qh + SZ;
    short* kh  = ql + SZ;
    short* kl  = kh + SZ;
    short* vh  = kl + SZ;
    short* Wth = vh + SZ;                        // [384][1024]
    short* Wtl = Wth + (size_t)384 * C_;

    wprep<<<dim3(384), dim3(256), 0, stream>>>(Wq, Wk, Wv, Wth, Wtl);
    gemm_proj<<<dim3(B_ * T_ / BM, 3), dim3(256), 0, stream>>>(
        x, Wth, Wtl, bq, bk, bv, qh, ql, kh, kl, vh);
    attn_mfma<<<dim3(T_ / TQA, B_), dim3(128), 0, stream>>>(
        qh, ql, kh, kl, vh, out);
}

// Round 5
// 151.810 us; speedup vs baseline: 4.6065x; 1.6534x over previous
//
#include <hip/hip_runtime.h>
#include <math.h>

#define B_ 8
#define T_ 2048
#define C_ 1024
#define H_ 128

#define TQA 32           // q rows per attention block (2 row-groups x 16)
#define TKA 32           // k/v rows per tile (one 32-key tile per MFMA K)

#define BM 128
#define BN 128
#define BK 64

typedef __attribute__((ext_vector_type(8))) short s16x8;
typedef __attribute__((ext_vector_type(4))) short s16x4;
typedef __attribute__((ext_vector_type(4))) float f32x4;

__device__ __forceinline__ short f2bf(float f) {
    unsigned u = __float_as_uint(f);
    u += 0x7fffu + ((u >> 16) & 1u);       // RNE
    return (short)(u >> 16);
}
__device__ __forceinline__ float bf2f(short s) {
    return __uint_as_float(((unsigned)(unsigned short)s) << 16);
}

// ---------------------------------------------------------------------------
// Kernel 0: W prep — transpose W[k][h] (q,k,v) into Wt[n][k] hi/lo bf16.
// ---------------------------------------------------------------------------
__global__ __launch_bounds__(256) void wprep(
    const float* __restrict__ Wq, const float* __restrict__ Wk,
    const float* __restrict__ Wv,
    short* __restrict__ Wth, short* __restrict__ Wtl)
{
    const int n   = blockIdx.x;           // 0..383
    const int mat = n >> 7;
    const int h   = n & 127;
    const float* W = (mat == 0) ? Wq : (mat == 1) ? Wk : Wv;
    for (int k = threadIdx.x; k < C_; k += 256) {
        const float w = W[(size_t)k * H_ + h];
        const short hi = f2bf(w);
        Wth[(size_t)n * C_ + k] = hi;
        Wtl[(size_t)n * C_ + k] = f2bf(w - bf2f(hi));
    }
}

// ---------------------------------------------------------------------------
// Kernel 1: 3-term hi/lo bf16 MFMA GEMM (unchanged from round 4).
// ---------------------------------------------------------------------------
__global__ __launch_bounds__(256, 2) void gemm_proj(
    const float* __restrict__ x,
    const short* __restrict__ Wth, const short* __restrict__ Wtl,
    const float* __restrict__ bq, const float* __restrict__ bk,
    const float* __restrict__ bv,
    short* __restrict__ qh, short* __restrict__ ql,
    short* __restrict__ kh, short* __restrict__ kl,
    short* __restrict__ vh)
{
    __shared__ short Ah[BM * BK];
    __shared__ short Al[BM * BK];
    __shared__ short Bh[BN * BK];
    __shared__ short Bl[BN * BK];

    const int tid  = threadIdx.x;
    const int my   = blockIdx.y;
    const long m0  = (long)blockIdx.x * BM;
    const int lane = tid & 63;
    const int w    = tid >> 6;
    const int wr   = w >> 1, wc = w & 1;
    const int lg   = lane >> 4, lc = lane & 15;

    float4 xr[8];

    #define LOAD_X(k0)                                                        \
        _Pragma("unroll")                                                     \
        for (int it = 0; it < 8; ++it) {                                      \
            const int i  = tid + it * 256;                                    \
            const int r  = i >> 4;                                            \
            const int k4 = i & 15;                                            \
            xr[it] = *(const float4*)&x[(m0 + r) * C_ + (k0) + k4 * 4];       \
        }

    #define STORE_LDS(k0)                                                     \
        _Pragma("unroll")                                                     \
        for (int it = 0; it < 8; ++it) {                                      \
            const int i  = tid + it * 256;                                    \
            const int r  = i >> 4;                                            \
            const int k4 = i & 15;                                            \
            s16x4 hi4, lo4;                                                   \
            _Pragma("unroll")                                                 \
            for (int j = 0; j < 4; ++j) {                                     \
                const float f = ((const float*)&xr[it])[j];                   \
                const short h8 = f2bf(f);                                     \
                hi4[j] = h8; lo4[j] = f2bf(f - bf2f(h8));                     \
            }                                                                 \
            const int off = r * 64 + (((k4 >> 1) ^ (r & 7)) << 3)             \
                          + ((k4 & 1) << 2);                                  \
            *(s16x4*)&Ah[off] = hi4;                                          \
            *(s16x4*)&Al[off] = lo4;                                          \
        }                                                                     \
        _Pragma("unroll")                                                     \
        for (int it = 0; it < 4; ++it) {                                      \
            const int i = tid + it * 256;                                     \
            const int r = i >> 3;                                             \
            const int s = i & 7;                                              \
            const size_t g = (size_t)(my * BN + r) * C_ + (k0) + s * 8;       \
            const int off = r * 64 + ((s ^ (r & 7)) << 3);                    \
            *(s16x8*)&Bh[off] = *(const s16x8*)&Wth[g];                       \
            *(s16x8*)&Bl[off] = *(const s16x8*)&Wtl[g];                       \
        }

    f32x4 acc[4][4];
    #pragma unroll
    for (int m = 0; m < 4; ++m)
        #pragma unroll
        for (int n = 0; n < 4; ++n) acc[m][n] = (f32x4){0.f, 0.f, 0.f, 0.f};

    LOAD_X(0);
    STORE_LDS(0);
    __syncthreads();

    for (int kt = 0; kt < C_ / BK; ++kt) {
        if (kt < C_ / BK - 1) LOAD_X((kt + 1) * BK);

        #pragma unroll
        for (int kc = 0; kc < 2; ++kc) {
            s16x8 afh[4], afl[4], bfh[4], bfl[4];
            #pragma unroll
            for (int m = 0; m < 4; ++m) {
                const int r = wr * 64 + m * 16 + lc;
                const int off = r * 64 + ((((kc << 2) + lg) ^ (r & 7)) << 3);
                afh[m] = *(const s16x8*)&Ah[off];
                afl[m] = *(const s16x8*)&Al[off];
            }
            #pragma unroll
            for (int n = 0; n < 4; ++n) {
                const int r = wc * 64 + n * 16 + lc;
                const int off = r * 64 + ((((kc << 2) + lg) ^ (r & 7)) << 3);
                bfh[n] = *(const s16x8*)&Bh[off];
                bfl[n] = *(const s16x8*)&Bl[off];
            }
            #pragma unroll
            for (int m = 0; m < 4; ++m)
                #pragma unroll
                for (int n = 0; n < 4; ++n) {
                    acc[m][n] = __builtin_amdgcn_mfma_f32_16x16x32_bf16(afh[m], bfh[n], acc[m][n], 0, 0, 0);
                    acc[m][n] = __builtin_amdgcn_mfma_f32_16x16x32_bf16(afh[m], bfl[n], acc[m][n], 0, 0, 0);
                    acc[m][n] = __builtin_amdgcn_mfma_f32_16x16x32_bf16(afl[m], bfh[n], acc[m][n], 0, 0, 0);
                }
        }
        __syncthreads();
        if (kt < C_ / BK - 1) {
            STORE_LDS((kt + 1) * BK);
            __syncthreads();
        }
    }

    const float* bias = (my == 0) ? bq : (my == 1) ? bk : bv;
    short* oh = (my == 0) ? qh : (my == 1) ? kh : vh;
    short* ol = (my == 0) ? ql : kl;

    #pragma unroll
    for (int n = 0; n < 4; ++n) {
        const int h = wc * 64 + n * 16 + lc;
        const float bv_ = bias[h];
        #pragma unroll
        for (int m = 0; m < 4; ++m) {
            #pragma unroll
            for (int rr = 0; rr < 4; ++rr) {
                const long row = m0 + wr * 64 + m * 16 + lg * 4 + rr;
                const float val = acc[m][n][rr] + bv_;
                const short hi = f2bf(val);
                oh[(size_t)row * H_ + h] = hi;
                if (my < 2) ol[(size_t)row * H_ + h] = f2bf(val - bf2f(hi));
            }
        }
    }
}

// ---------------------------------------------------------------------------
// Kernel 1b: vtrans — vh [B][T][H] -> vtg [B][H][T] (bf16), LDS 64x64 tiles.
// ---------------------------------------------------------------------------
__global__ __launch_bounds__(256) void vtrans(
    const short* __restrict__ vh, short* __restrict__ vtg)
{
    __shared__ short tbuf[64][72];
    const int b  = blockIdx.z;
    const int t0 = blockIdx.x * 64;
    const int h0 = blockIdx.y * 64;
    const int tid = threadIdx.x;
    const size_t bo  = (size_t)b * T_ * H_;
    const size_t vbo = (size_t)b * H_ * T_;

    #pragma unroll
    for (int it = 0; it < 2; ++it) {
        const int u = tid + it * 256;
        const int r = u >> 3, c8 = u & 7;
        *(s16x8*)&tbuf[r][c8 * 8] =
            *(const s16x8*)&vh[bo + (size_t)(t0 + r) * H_ + h0 + c8 * 8];
    }
    __syncthreads();
    #pragma unroll
    for (int it = 0; it < 2; ++it) {
        const int u = tid + it * 256;
        const int t8 = u >> 6, hr = u & 63;
        s16x8 v;
        #pragma unroll
        for (int j = 0; j < 8; ++j) v[j] = tbuf[t8 * 8 + j][hr];
        *(s16x8*)&vtg[vbo + (size_t)(h0 + hr) * T_ + t0 + t8 * 8] = v;
    }
}

// ---------------------------------------------------------------------------
// Kernel 2: causal flash attention v3.
// grid (64, 8), 256 threads = 4 waves: wave w -> rg=w>>1 (16 q rows),
// kp=w&1 (key-tile parity). Block-level split-K; pair-combine in LDS.
// Per round: both parities' 32-key tiles staged (double-buffered by parity),
// next round prefetched into regs (T14). LDS swizzled, conflict-checked.
// ---------------------------------------------------------------------------
__global__ __launch_bounds__(256, 2) void attn_v3(
    const short* __restrict__ qhg, const short* __restrict__ qlg,
    const short* __restrict__ khg, const short* __restrict__ klg,
    const short* __restrict__ vtg, float* __restrict__ out)
{
    __shared__ short Kh[2][TKA * 128];    // 16 KB
    __shared__ short Kl[2][TKA * 128];    // 16 KB
    __shared__ short Vt[2][128 * TKA];    // 16 KB  (rows = h, cols = key)
    __shared__ short Pw[4][16 * 40];      // 5 KB   (per-wave P, stride 40)
    __shared__ float Ocmb[2][64][33];     // 16.9 KB
    __shared__ float Mcmb[2][64][8];      // 4 KB

    const int tid  = threadIdx.x;
    const int lane = tid & 63;
    const int w    = tid >> 6;
    const int rg   = w >> 1;
    const int kp   = w & 1;
    const int lg   = lane >> 4;
    const int lc   = lane & 15;
    const int b    = blockIdx.y;
    const int tile = 63 - (int)blockIdx.x;     // LPT: longest first
    const int t0   = tile * TQA;

    const size_t bo  = (size_t)b * T_ * H_;
    const size_t vbo = (size_t)b * H_ * T_;

    // ---- Q fragments for this wave's row-group ----
    s16x8 qfh[4], qfl[4];
    {
        const size_t rbase = bo + (size_t)(t0 + rg * 16 + lc) * H_;
        #pragma unroll
        for (int kc = 0; kc < 4; ++kc) {
            qfh[kc] = *(const s16x8*)(qhg + rbase + kc * 32 + lg * 8);
            qfl[kc] = *(const s16x8*)(qlg + rbase + kc * 32 + lg * 8);
        }
    }

    f32x4 Oacc[8];
    #pragma unroll
    for (int ht = 0; ht < 8; ++ht) Oacc[ht] = (f32x4){0.f, 0.f, 0.f, 0.f};
    float m_run[4] = {-INFINITY, -INFINITY, -INFINITY, -INFINITY};
    float l_run[4] = {0.f, 0.f, 0.f, 0.f};

    const int nt = tile + 1;              // 32-key tiles
    const int R  = (nt + 1) >> 1;         // rounds (2 tiles per round)

    s16x8 pf[12];                         // prefetch regs: 48 KB / 256 thr

    // 12 chunks/thread: g = tid + it*256; arr = g>>10 (Kh,Kl,Vt);
    // cid = g&1023; buf = cid>>9; idx = cid&511.
    #define ISSUE_LOADS(rr_)                                                  \
        _Pragma("unroll")                                                     \
        for (int it = 0; it < 12; ++it) {                                     \
            const int g   = tid + it * 256;                                   \
            const int arr = g >> 10;                                          \
            const int cid = g & 1023;                                         \
            const int buf = cid >> 9;                                         \
            const int idx = cid & 511;                                        \
            int kt_ = 2 * (rr_) + buf; if (kt_ >= nt) kt_ = nt - 1;           \
            const int s0_ = kt_ * TKA;                                        \
            if (arr <= 1) {                                                   \
                const int key = idx >> 4, hc = idx & 15;                      \
                const size_t a = bo + (size_t)(s0_ + key) * H_ + hc * 8;      \
                pf[it] = *(const s16x8*)((arr == 0 ? khg : klg) + a);         \
            } else {                                                          \
                const int hh = idx >> 2, k4 = idx & 3;                        \
                pf[it] = *(const s16x8*)(vtg + vbo + (size_t)hh * T_          \
                                         + s0_ + k4 * 8);                     \
            }                                                                 \
        }

    #define WRITE_LDS()                                                       \
        _Pragma("unroll")                                                     \
        for (int it = 0; it < 12; ++it) {                                     \
            const int g   = tid + it * 256;                                   \
            const int arr = g >> 10;                                          \
            const int cid = g & 1023;                                         \
            const int buf = cid >> 9;                                         \
            const int idx = cid & 511;                                        \
            if (arr <= 1) {                                                   \
                const int key = idx >> 4, hc = idx & 15;                      \
                const int off = key * 128 + ((hc ^ (key & 7)) << 3);          \
                *(s16x8*)&((arr == 0 ? Kh : Kl)[buf][off]) = pf[it];          \
            } else {                                                          \
                const int hh = idx >> 2, k4 = idx & 3;                        \
                const int off = hh * 32 + ((k4 ^ (hh & 3)) << 3);             \
                *(s16x8*)&Vt[buf][off] = pf[it];                              \
            }                                                                 \
        }

    ISSUE_LOADS(0);

    for (int r = 0; r < R; ++r) {
        WRITE_LDS();                      // implicit vmcnt wait on pf
        __syncthreads();
        if (r + 1 < R) ISSUE_LOADS(r + 1);

        const int kt = 2 * r + kp;
        if (kt < nt) {
            const int s0 = kt * TKA;

            // ---- S = Q K^T (2 col-tiles x 4 k-chunks x 3 hi/lo terms) ----
            f32x4 sfr[2];
            sfr[0] = (f32x4){0.f, 0.f, 0.f, 0.f};
            sfr[1] = (f32x4){0.f, 0.f, 0.f, 0.f};
            #pragma unroll
            for (int kc = 0; kc < 4; ++kc) {
                #pragma unroll
                for (int ct = 0; ct < 2; ++ct) {
                    const int key = ct * 16 + lc;
                    const int off = key * 128
                                  + ((kc * 32 + lg * 8) ^ ((key & 7) << 3));
                    const s16x8 bh = *(const s16x8*)&Kh[kp][off];
                    const s16x8 bl = *(const s16x8*)&Kl[kp][off];
                    sfr[ct] = __builtin_amdgcn_mfma_f32_16x16x32_bf16(qfh[kc], bh, sfr[ct], 0, 0, 0);
                    sfr[ct] = __builtin_amdgcn_mfma_f32_16x16x32_bf16(qfl[kc], bh, sfr[ct], 0, 0, 0);
                    sfr[ct] = __builtin_amdgcn_mfma_f32_16x16x32_bf16(qfh[kc], bl, sfr[ct], 0, 0, 0);
                }
            }

            // ---- causal mask (uniform, applied every tile) ----
            #pragma unroll
            for (int ct = 0; ct < 2; ++ct) {
                const int key_g = s0 + ct * 16 + lc;
                #pragma unroll
                for (int rr = 0; rr < 4; ++rr) {
                    const int row_g = t0 + rg * 16 + lg * 4 + rr;
                    if (key_g > row_g) sfr[ct][rr] = -INFINITY;
                }
            }

            // ---- online softmax (16-lane shfl_xor reduce) ----
            float mx[4];
            #pragma unroll
            for (int rr = 0; rr < 4; ++rr)
                mx[rr] = fmaxf(sfr[0][rr], sfr[1][rr]);
            #pragma unroll
            for (int d = 1; d < 16; d <<= 1)
                #pragma unroll
                for (int rr = 0; rr < 4; ++rr)
                    mx[rr] = fmaxf(mx[rr], __shfl_xor(mx[rr], d, 64));

            float sc[4], sum[4];
            #pragma unroll
            for (int rr = 0; rr < 4; ++rr) {
                const float mnew = fmaxf(m_run[rr], mx[rr]);
                sc[rr] = __expf(m_run[rr] - mnew);
                m_run[rr] = mnew;
                sum[rr] = 0.f;
            }
            #pragma unroll
            for (int ct = 0; ct < 2; ++ct)
                #pragma unroll
                for (int rr = 0; rr < 4; ++rr) {
                    const float p = __expf(sfr[ct][rr] - m_run[rr]);
                    sfr[ct][rr] = p;
                    sum[rr] += p;
                }
            #pragma unroll
            for (int d = 1; d < 16; d <<= 1)
                #pragma unroll
                for (int rr = 0; rr < 4; ++rr)
                    sum[rr] += __shfl_xor(sum[rr], d, 64);
            #pragma unroll
            for (int rr = 0; rr < 4; ++rr)
                l_run[rr] = l_run[rr] * sc[rr] + sum[rr];

            #pragma unroll
            for (int ht = 0; ht < 8; ++ht)
                #pragma unroll
                for (int rr = 0; rr < 4; ++rr) Oacc[ht][rr] *= sc[rr];

            // ---- P to LDS (per-wave), then PV: one K=32 MFMA per h-tile ----
            #pragma unroll
            for (int ct = 0; ct < 2; ++ct)
                #pragma unroll
                for (int rr = 0; rr < 4; ++rr)
                    Pw[w][(lg * 4 + rr) * 40 + ct * 16 + lc] = f2bf(sfr[ct][rr]);

            const s16x8 pa = *(const s16x8*)&Pw[w][lc * 40 + lg * 8];
            #pragma unroll
            for (int ht = 0; ht < 8; ++ht) {
                const int h = ht * 16 + lc;
                const int off = h * 32 + ((lg * 8) ^ ((h & 3) << 3));
                const s16x8 vb = *(const s16x8*)&Vt[kp][off];
                Oacc[ht] = __builtin_amdgcn_mfma_f32_16x16x32_bf16(pa, vb, Oacc[ht], 0, 0, 0);
            }
        }
        __syncthreads();
    }

    // ---- pair combine: odd parity publishes, even parity merges+writes ----
    if (kp == 1) {
        float* dst = &Ocmb[rg][lane][0];
        #pragma unroll
        for (int ht = 0; ht < 8; ++ht)
            #pragma unroll
            for (int rr = 0; rr < 4; ++rr) dst[ht * 4 + rr] = Oacc[ht][rr];
        #pragma unroll
        for (int rr = 0; rr < 4; ++rr) {
            Mcmb[rg][lane][rr]     = m_run[rr];
            Mcmb[rg][lane][4 + rr] = l_run[rr];
        }
    }
    __syncthreads();
    if (kp == 0) {
        float a0[4], a1[4], inv[4];
        #pragma unroll
        for (int rr = 0; rr < 4; ++rr) {
            const float m1 = Mcmb[rg][lane][rr];
            const float l1 = Mcmb[rg][lane][4 + rr];
            const float M  = fmaxf(m_run[rr], m1);
            a0[rr] = __expf(m_run[rr] - M);
            a1[rr] = __expf(m1 - M);
            inv[rr] = 1.f / (l_run[rr] * a0[rr] + l1 * a1[rr]);
        }
        const float* src = &Ocmb[rg][lane][0];
        float* ob = out + bo + (size_t)(t0 + rg * 16) * H_;
        #pragma unroll
        for (int ht = 0; ht < 8; ++ht)
            #pragma unroll
            for (int rr = 0; rr < 4; ++rr) {
                const float val = (Oacc[ht][rr] * a0[rr]
                                 + src[ht * 4 + rr] * a1[rr]) * inv[rr];
                ob[(size_t)(lg * 4 + rr) * H_ + ht * 16 + lc] = val;
            }
    }
}

// ---------------------------------------------------------------------------
extern "C" void kernel_launch(void* const* d_in, const int* in_sizes, int n_in,
                              void* d_out, int out_size, void* d_ws, size_t ws_size,
                              hipStream_t stream)
{
    const float* x  = (const float*)d_in[0];
    const float* Wq = (const float*)d_in[1];
    const float* bq = (const float*)d_in[2];
    const float* Wk = (const float*)d_in[3];
    const float* bk = (const float*)d_in[4];
    const float* Wv = (const float*)d_in[5];
    const float* bv = (const float*)d_in[6];
    float* out = (float*)d_out;

    const size_t SZ = (size_t)B_ * T_ * H_;     // 2M elems
    short* qh  = (short*)d_ws;
    short* ql  = qh + SZ;
    short* kh  = ql + SZ;
    short* kl  = kh + SZ;
    short* vh  = kl + SZ;
    short* Wth = vh + SZ;                        // [384][1024]
    short* Wtl = Wth + (size_t)384 * C_;
    short* vtg = Wtl + (size_t)384 * C_;         // [B][H][T]

    wprep<<<dim3(384), dim3(256), 0, stream>>>(Wq, Wk, Wv, Wth, Wtl);
    gemm_proj<<<dim3(B_ * T_ / BM, 3), dim3(256), 0, stream>>>(
        x, Wth, Wtl, bq, bk, bv, qh, ql, kh, kl, vh);
    vtrans<<<dim3(T_ / 64, H_ / 64, B_), dim3(256), 0, stream>>>(vh, vtg);
    attn_v3<<<dim3(T_ / TQA, B_), dim3(256), 0, stream>>>(
        qh, ql, kh, kl, vtg, out);
}